// Round 5
// baseline (445.281 us; speedup 1.0000x reference)
//
#include <hip/hip_runtime.h>

// ErosionLayer: B=16, W=512, ITERS=10, fp32.
// r1/r2/r4 (unfused, correctly-rounded fp32) all landed at absmax 0.21875;
// pure-numpy semantics are therefore NOT the comparator. Theory: the reference
// trajectory went through XLA, which greedily contracts single-use fmul into
// adjacent fadd/fsub (LLVM DAGCombiner patterns). This kernel reproduces that
// exact contraction set via explicit fmaf(), with contract(off) elsewhere so
// the HIP compiler adds/removes nothing. Division/sqrt stay correctly rounded
// (double-emulated, flag-immune); XLA keeps IEEE div here (CELL_W not pow2).
#pragma clang fp contract(off)

constexpr int WW   = 512;
constexpr int NPIX = WW * WW;      // 2^18
constexpr int NTOT = 16 * NPIX;

__device__ __forceinline__ float f_div(float a, float b) { return (float)((double)a / (double)b); }
__device__ __forceinline__ float f_sqrt(float a)         { return (float)sqrt((double)a); }

__global__ __launch_bounds__(256) void erosion_init(
    const float* __restrict__ in, float* __restrict__ terr,
    float* __restrict__ sed, float* __restrict__ wat, float* __restrict__ vel)
{
    #pragma clang fp contract(off)
    int idx = blockIdx.x * 256 + threadIdx.x;
    terr[idx] = f_div(1.0f - in[idx], 2.0f);
    sed[idx] = 0.0f;
    wat[idx] = 0.0f;
    vel[idx] = 0.0f;
}

__global__ __launch_bounds__(256) void erosion_step(
    const float* __restrict__ terr_in, float* __restrict__ terr_out,
    float* __restrict__ sed, float* __restrict__ wat, float* __restrict__ vel,
    const float* __restrict__ rain, const float* __restrict__ gnoise,
    const float* __restrict__ s_rain_rate, const float* __restrict__ s_evap,
    const float* __restrict__ s_minhd, const float* __restrict__ s_heps,
    const float* __restrict__ s_grav, const float* __restrict__ s_scc,
    const float* __restrict__ s_diss, const float* __restrict__ s_depo,
    int final_flag)
{
    #pragma clang fp contract(off)
    const float CELLW = 0.390625f;          // 200/512, exact
    int idx = blockIdx.x * 256 + threadIdx.x;
    int rem = idx & (NPIX - 1);
    int r   = rem >> 9;
    int c   = rem & (WW - 1);
    const float* tb = terr_in + (long)(idx - rem);

    float rr    = fmaxf(s_rain_rate[0], 0.0f);
    float evapr = fmaxf(s_evap[0], 0.0f);
    float minhd = s_minhd[0];
    float heps  = s_heps[0];
    float gravr = fmaxf(s_grav[0], 0.0f);
    float sccr  = fmaxf(s_scc[0], 0.0f);
    float diss  = s_diss[0];
    float depo  = s_depo[0];

    float t_c = tb[rem];

    // water = water + relu(rain_rate)*rain  -> fma(rr, rain, water)
    float w = fmaf(rr, rain[rem], wat[idx]);

    // --- simple_gradient; boundary t*1.1 - t -> fma(t, 1.1, -t) ---
    float dx, dy;
    if      (r == 0)      dx = 0.5f * fmaf(t_c, 1.1f, -t_c);
    else if (r == WW - 1) dx = 0.5f * fmaf(t_c, 0.9f, -t_c);
    else                  dx = 0.5f * (tb[rem + WW] - tb[rem - WW]);
    if      (c == 0)      dy = 0.5f * fmaf(t_c, 1.1f, -t_c);
    else if (c == WW - 1) dy = 0.5f * fmaf(t_c, 0.9f, -t_c);
    else                  dy = 0.5f * (tb[rem + 1] - tb[rem - 1]);

    // dx*dx + dy*dy + eps -> fma(dx,dx, dy*dy) + eps
    float mag = f_sqrt(fmaf(dx, dx, dy * dy) + 1e-11f);

    float rX  = gnoise[rem];
    float rY  = f_sqrt(fmaf(-rX, rX, 1.0f));            // 1 - rX*rX -> fnma

    float factor = fmaxf(1e-10f - mag, 0.0f);           // always 0; kept for fidelity
    float den = mag + factor;
    float fdx = f_div(fmaf(factor, rX, dx), den);       // (dx + factor*rX)/den
    float fdy = f_div(fmaf(factor, rY, dy), den);

    // --- bilinear_sample(terrain, -gradient) ---
    float fx  = (float)c + (-fdx);
    float fy  = (float)r + (-fdy);
    float x0f = floorf(fx), y0f = floorf(fy);
    float wx1 = fx - x0f;
    float wy1 = fy - y0f;
    int x0 = (int)x0f, y0 = (int)y0f;
    int x1 = x0 + 1,   y1 = y0 + 1;

    bool vx0 = (x0 >= 0) & (x0 < WW);
    bool vx1 = (x1 >= 0) & (x1 < WW);
    bool vy0 = (y0 >= 0) & (y0 < WW);
    bool vy1 = (y1 >= 0) & (y1 < WW);
    int x0c = min(max(x0, 0), WW - 1), x1c = min(max(x1, 0), WW - 1);
    int y0c = min(max(y0, 0), WW - 1), y1c = min(max(y1, 0), WW - 1);

    float g00 = (vx0 && vy0) ? (tb[y0c * WW + x0c] - 1.0f) : 0.0f;
    float g10 = (vx1 && vy0) ? (tb[y0c * WW + x1c] - 1.0f) : 0.0f;
    float g01 = (vx0 && vy1) ? (tb[y1c * WW + x0c] - 1.0f) : 0.0f;
    float g11 = (vx1 && vy1) ? (tb[y1c * WW + x1c] - 1.0f) : 0.0f;

    float wx0 = 1.0f - wx1;
    float wy0 = 1.0f - wy1;
    // (1-wx1)*g00 + wx1*g10 -> fma(wx0, g00, wx1*g10); same outer level
    float rowA = fmaf(wx0, g00, wx1 * g10);
    float rowB = fmaf(wx0, g01, wx1 * g11);
    float bil  = fmaf(wy0, rowA, wy1 * rowB);
    float neighbor = bil + 1.0f;

    float hd = t_c - neighbor;

    // --- state update ---
    float v = vel[idx];
    float s = sed[idx];

    float hds  = ((hd - heps) > 0.0f) ? 1.0f : 0.0f;     // sign(relu(hd-eps))
    float nhd  = hds * fmaxf(hd, minhd);
    float q1 = f_div(nhd, CELLW);
    float q2 = q1 * v;
    float q3 = q2 * w;
    // sdiff = s - (q3*scc) -> fma(-q3, scc, s)
    float sdiff = fmaf(-q3, sccr, s);
    float ftb   = (hd < 0.0f) ? 1.0f : 0.0f;             // relu(sign(-hd))
    float first = fminf(fmaxf(-hd, 0.0f), s);
    float ra = fmaxf(sdiff * depo, 0.0f);
    float rb = fmaxf((-sdiff) * diss, 0.0f);
    // first + (1-ftb)*(ra-rb) -> fma(1-ftb, ra-rb, first)
    float deparg = fmaf(1.0f - ftb, ra - rb, first);
    float dep    = fmaxf(-fmaxf(hd, 0.0f), deparg);

    float s_new = s - dep;
    float t_new = t_c + dep;

    // --- displace: (sel(t1) + rm*a) + sel(t3); middle mul fuses into first add ---
    float rn = fmaxf(-fdy, 0.0f);
    float rm = fmaxf(1.0f - fabsf(fdy), 0.0f);
    float rp = fmaxf(fdy, 0.0f);

    float s1 = (c == WW - 1) ? 0.0f : rn * s_new;
    float s3 = (c == 0)      ? 0.0f : rp * s_new;
    sed[idx] = fmaf(rm, s_new, s1) + s3;

    float w1 = (c == WW - 1) ? 0.0f : rn * w;
    float w3 = (c == 0)      ? 0.0f : rp * w;
    float wd = fmaf(rm, w, w1) + w3;
    wat[idx] = wd * (1.0f - evapr);

    vel[idx] = f_div(gravr * hd, CELLW);                 // (relu(g)*hd)/CELL_W

    if (final_flag) {
        float a = fmaf(-t_new, 2.0f, 1.0f);              // 1 - t*2 -> fnma
        float bq = 1.0f + a;
        terr_out[idx] = fmaxf(bq, 0.0f) - 1.0f;
    } else {
        terr_out[idx] = t_new;
    }
}

extern "C" void kernel_launch(void* const* d_in, const int* in_sizes, int n_in,
                              void* d_out, int out_size, void* d_ws, size_t ws_size,
                              hipStream_t stream) {
    const float* in_terr    = (const float*)d_in[0];
    const float* rain_all   = (const float*)d_in[1];  // (1,10,W,W)
    const float* gnoise_all = (const float*)d_in[2];  // (1,10,W,W)
    const float* p_rr       = (const float*)d_in[3];
    const float* p_evap     = (const float*)d_in[4];
    const float* p_minhd    = (const float*)d_in[5];
    const float* p_heps     = (const float*)d_in[6];
    const float* p_grav     = (const float*)d_in[7];
    const float* p_scc      = (const float*)d_in[8];
    const float* p_diss     = (const float*)d_in[9];
    const float* p_depo     = (const float*)d_in[10];

    float* T0  = (float*)d_out;          // terrain buffer 0 (also final output)
    float* ws  = (float*)d_ws;
    float* T1  = ws;                     // terrain buffer 1
    float* sed = ws + (size_t)NTOT;
    float* wat = ws + (size_t)2 * NTOT;
    float* vel = ws + (size_t)3 * NTOT;

    dim3 grid(NTOT / 256), block(256);
    erosion_init<<<grid, block, 0, stream>>>(in_terr, T0, sed, wat, vel);

    for (int it = 0; it < 10; ++it) {
        const float* tin  = (it & 1) ? T1 : T0;
        float*       tout = (it & 1) ? T0 : T1;
        erosion_step<<<grid, block, 0, stream>>>(
            tin, tout, sed, wat, vel,
            rain_all + (size_t)it * NPIX, gnoise_all + (size_t)it * NPIX,
            p_rr, p_evap, p_minhd, p_heps, p_grav, p_scc, p_diss, p_depo,
            (it == 9) ? 1 : 0);
    }
}

// Round 6
// 441.638 us; speedup vs baseline: 1.0082x; 1.0082x over previous
//
#include <hip/hip_runtime.h>

// ErosionLayer: B=16, W=512, ITERS=10, fp32. PASSING recipe (r5, absmax 0.027):
// XLA-style greedy FMA contraction encoded with explicit fmaf() at the exact
// sites, contract(off) everywhere else, correctly-rounded fp32 div/sqrt.
// r6: native fp32 '/' and sqrtf (hipcc default = correctly rounded, so
// bit-identical to r5's double-emulated versions) — removes ~15-20 us/step
// of fp64 VALU serialization. DO NOT change op order or fusion sites.
#pragma clang fp contract(off)

constexpr int WW   = 512;
constexpr int NPIX = WW * WW;      // 2^18
constexpr int NTOT = 16 * NPIX;

__global__ __launch_bounds__(256) void erosion_init(
    const float* __restrict__ in, float* __restrict__ terr,
    float* __restrict__ sed, float* __restrict__ wat, float* __restrict__ vel)
{
    #pragma clang fp contract(off)
    int idx = blockIdx.x * 256 + threadIdx.x;
    terr[idx] = (1.0f - in[idx]) / 2.0f;
    sed[idx] = 0.0f;
    wat[idx] = 0.0f;
    vel[idx] = 0.0f;
}

__global__ __launch_bounds__(256) void erosion_step(
    const float* __restrict__ terr_in, float* __restrict__ terr_out,
    float* __restrict__ sed, float* __restrict__ wat, float* __restrict__ vel,
    const float* __restrict__ rain, const float* __restrict__ gnoise,
    const float* __restrict__ s_rain_rate, const float* __restrict__ s_evap,
    const float* __restrict__ s_minhd, const float* __restrict__ s_heps,
    const float* __restrict__ s_grav, const float* __restrict__ s_scc,
    const float* __restrict__ s_diss, const float* __restrict__ s_depo,
    int final_flag)
{
    #pragma clang fp contract(off)
    const float CELLW = 0.390625f;          // 200/512, exact
    int idx = blockIdx.x * 256 + threadIdx.x;
    int rem = idx & (NPIX - 1);
    int r   = rem >> 9;
    int c   = rem & (WW - 1);
    const float* tb = terr_in + (long)(idx - rem);

    float rr    = fmaxf(s_rain_rate[0], 0.0f);
    float evapr = fmaxf(s_evap[0], 0.0f);
    float minhd = s_minhd[0];
    float heps  = s_heps[0];
    float gravr = fmaxf(s_grav[0], 0.0f);
    float sccr  = fmaxf(s_scc[0], 0.0f);
    float diss  = s_diss[0];
    float depo  = s_depo[0];

    float t_c = tb[rem];

    // water = water + relu(rain_rate)*rain  -> fma
    float w = fmaf(rr, rain[rem], wat[idx]);

    // --- simple_gradient; boundary t*1.1 - t -> fma(t, 1.1, -t) ---
    float dx, dy;
    if      (r == 0)      dx = 0.5f * fmaf(t_c, 1.1f, -t_c);
    else if (r == WW - 1) dx = 0.5f * fmaf(t_c, 0.9f, -t_c);
    else                  dx = 0.5f * (tb[rem + WW] - tb[rem - WW]);
    if      (c == 0)      dy = 0.5f * fmaf(t_c, 1.1f, -t_c);
    else if (c == WW - 1) dy = 0.5f * fmaf(t_c, 0.9f, -t_c);
    else                  dy = 0.5f * (tb[rem + 1] - tb[rem - 1]);

    float mag = sqrtf(fmaf(dx, dx, dy * dy) + 1e-11f);

    float rX  = gnoise[rem];
    float rY  = sqrtf(fmaf(-rX, rX, 1.0f));             // 1 - rX*rX -> fnma

    float factor = fmaxf(1e-10f - mag, 0.0f);           // always 0; kept for fidelity
    float den = mag + factor;
    float fdx = fmaf(factor, rX, dx) / den;             // (dx + factor*rX)/den
    float fdy = fmaf(factor, rY, dy) / den;

    // --- bilinear_sample(terrain, -gradient) ---
    float fx  = (float)c + (-fdx);
    float fy  = (float)r + (-fdy);
    float x0f = floorf(fx), y0f = floorf(fy);
    float wx1 = fx - x0f;
    float wy1 = fy - y0f;
    int x0 = (int)x0f, y0 = (int)y0f;
    int x1 = x0 + 1,   y1 = y0 + 1;

    bool vx0 = (x0 >= 0) & (x0 < WW);
    bool vx1 = (x1 >= 0) & (x1 < WW);
    bool vy0 = (y0 >= 0) & (y0 < WW);
    bool vy1 = (y1 >= 0) & (y1 < WW);
    int x0c = min(max(x0, 0), WW - 1), x1c = min(max(x1, 0), WW - 1);
    int y0c = min(max(y0, 0), WW - 1), y1c = min(max(y1, 0), WW - 1);

    float g00 = (vx0 && vy0) ? (tb[y0c * WW + x0c] - 1.0f) : 0.0f;
    float g10 = (vx1 && vy0) ? (tb[y0c * WW + x1c] - 1.0f) : 0.0f;
    float g01 = (vx0 && vy1) ? (tb[y1c * WW + x0c] - 1.0f) : 0.0f;
    float g11 = (vx1 && vy1) ? (tb[y1c * WW + x1c] - 1.0f) : 0.0f;

    float wx0 = 1.0f - wx1;
    float wy0 = 1.0f - wy1;
    float rowA = fmaf(wx0, g00, wx1 * g10);
    float rowB = fmaf(wx0, g01, wx1 * g11);
    float bil  = fmaf(wy0, rowA, wy1 * rowB);
    float neighbor = bil + 1.0f;

    float hd = t_c - neighbor;

    // --- state update ---
    float v = vel[idx];
    float s = sed[idx];

    float hds  = ((hd - heps) > 0.0f) ? 1.0f : 0.0f;     // sign(relu(hd-eps))
    float nhd  = hds * fmaxf(hd, minhd);
    float q1 = nhd / CELLW;
    float q2 = q1 * v;
    float q3 = q2 * w;
    float sdiff = fmaf(-q3, sccr, s);                    // s - sed_cap
    float ftb   = (hd < 0.0f) ? 1.0f : 0.0f;             // relu(sign(-hd))
    float first = fminf(fmaxf(-hd, 0.0f), s);
    float ra = fmaxf(sdiff * depo, 0.0f);
    float rb = fmaxf((-sdiff) * diss, 0.0f);
    float deparg = fmaf(1.0f - ftb, ra - rb, first);
    float dep    = fmaxf(-fmaxf(hd, 0.0f), deparg);

    float s_new = s - dep;
    float t_new = t_c + dep;

    // --- displace: (sel(t1) + rm*a) + sel(t3) ---
    float rn = fmaxf(-fdy, 0.0f);
    float rm = fmaxf(1.0f - fabsf(fdy), 0.0f);
    float rp = fmaxf(fdy, 0.0f);

    float s1 = (c == WW - 1) ? 0.0f : rn * s_new;
    float s3 = (c == 0)      ? 0.0f : rp * s_new;
    sed[idx] = fmaf(rm, s_new, s1) + s3;

    float w1 = (c == WW - 1) ? 0.0f : rn * w;
    float w3 = (c == 0)      ? 0.0f : rp * w;
    float wd = fmaf(rm, w, w1) + w3;
    wat[idx] = wd * (1.0f - evapr);

    vel[idx] = (gravr * hd) / CELLW;

    if (final_flag) {
        float a = fmaf(-t_new, 2.0f, 1.0f);              // 1 - t*2 -> fnma
        float bq = 1.0f + a;
        terr_out[idx] = fmaxf(bq, 0.0f) - 1.0f;
    } else {
        terr_out[idx] = t_new;
    }
}

extern "C" void kernel_launch(void* const* d_in, const int* in_sizes, int n_in,
                              void* d_out, int out_size, void* d_ws, size_t ws_size,
                              hipStream_t stream) {
    const float* in_terr    = (const float*)d_in[0];
    const float* rain_all   = (const float*)d_in[1];  // (1,10,W,W)
    const float* gnoise_all = (const float*)d_in[2];  // (1,10,W,W)
    const float* p_rr       = (const float*)d_in[3];
    const float* p_evap     = (const float*)d_in[4];
    const float* p_minhd    = (const float*)d_in[5];
    const float* p_heps     = (const float*)d_in[6];
    const float* p_grav     = (const float*)d_in[7];
    const float* p_scc      = (const float*)d_in[8];
    const float* p_diss     = (const float*)d_in[9];
    const float* p_depo     = (const float*)d_in[10];

    float* T0  = (float*)d_out;          // terrain buffer 0 (also final output)
    float* ws  = (float*)d_ws;
    float* T1  = ws;                     // terrain buffer 1
    float* sed = ws + (size_t)NTOT;
    float* wat = ws + (size_t)2 * NTOT;
    float* vel = ws + (size_t)3 * NTOT;

    dim3 grid(NTOT / 256), block(256);
    erosion_init<<<grid, block, 0, stream>>>(in_terr, T0, sed, wat, vel);

    for (int it = 0; it < 10; ++it) {
        const float* tin  = (it & 1) ? T1 : T0;
        float*       tout = (it & 1) ? T0 : T1;
        erosion_step<<<grid, block, 0, stream>>>(
            tin, tout, sed, wat, vel,
            rain_all + (size_t)it * NPIX, gnoise_all + (size_t)it * NPIX,
            p_rr, p_evap, p_minhd, p_heps, p_grav, p_scc, p_diss, p_depo,
            (it == 9) ? 1 : 0);
    }
}